// Round 1
// 211.198 us; speedup vs baseline: 1.0500x; 1.0500x over previous
//
#include <hip/hip_runtime.h>

#define BH_ 32
#define S_ 2048
#define D_ 64
#define DQK 128
#define BQ 128   // q rows per block (4 waves x 32 q-rows each)
#define BK 64    // kv rows per tile
#define LDV 72   // Ps row stride: 144B (balanced banks for b64 write / b128 read)

typedef unsigned short u16;
typedef u16 u16x4 __attribute__((ext_vector_type(4)));
typedef u16 u16x8 __attribute__((ext_vector_type(8)));
typedef __bf16 bf16x8 __attribute__((ext_vector_type(8)));
typedef float f32x4 __attribute__((ext_vector_type(4)));

__device__ __forceinline__ u16 f2bf_rne(float f) {
  unsigned u = __builtin_bit_cast(unsigned, f);
  u += 0x7fffu + ((u >> 16) & 1u);
  return (u16)(u >> 16);
}
__device__ __forceinline__ u16 f2bf_fast(float f) {  // round-half-up
  unsigned u = __builtin_bit_cast(unsigned, f);
  u += 0x8000u;
  return (u16)(u >> 16);
}
__device__ __forceinline__ bf16x8 ld8(const u16* p) {
  return __builtin_bit_cast(bf16x8, *(const u16x8*)p);
}
// 16B global -> LDS DMA. LDS dest must be wave-uniform base + lane*16.
__device__ __forceinline__ void g2l16(const u16* g, u16* l) {
  __builtin_amdgcn_global_load_lds(
      (const __attribute__((address_space(1))) unsigned int*)g,
      (__attribute__((address_space(3))) unsigned int*)l, 16, 0, 0);
}

#define COEF 0.1803368801111204f  // (1/8) * log2(e), folded into Q conversion

// ---------------- prep: Kc = bf16 [K|Kp] concat; Vt = bf16 V-transposed ----
// Kc: [bh][s][128], 16B-chunk index XOR-swizzled by (s&7)  (both-sides swizzle:
//     fa3 stages linearly via global_load_lds and un-XORs on ds_read)
// Vt: [bh][kt][d=64][kv=64], 16B-chunk index XOR-swizzled by (d&7)
__global__ __launch_bounds__(256)
void prep_kernel(const float* __restrict__ K, const float* __restrict__ V,
                 const float* __restrict__ Kp,
                 u16* __restrict__ Kc, u16* __restrict__ Vt) {
  __shared__ float Ls[64][65];
  int b = blockIdx.x;
  if (b < 4096) {
    // Kc: each thread converts 8 consecutive cols (always within one tensor)
    int t = b * 256 + threadIdx.x;          // 1,048,576 threads
    int col8 = (t & 15) * 8;
    int s    = (t >> 4) & 2047;
    int bh   = t >> 15;
    const float* src = (col8 < 64) ? (K  + ((size_t)bh * S_ + s) * D_ + col8)
                                   : (Kp + ((size_t)bh * S_ + s) * D_ + (col8 - 64));
    float4 v0 = *(const float4*)src;
    float4 v1 = *(const float4*)(src + 4);
    u16x8 w;
    w[0] = f2bf_rne(v0.x); w[1] = f2bf_rne(v0.y); w[2] = f2bf_rne(v0.z); w[3] = f2bf_rne(v0.w);
    w[4] = f2bf_rne(v1.x); w[5] = f2bf_rne(v1.y); w[6] = f2bf_rne(v1.z); w[7] = f2bf_rne(v1.w);
    int swc = ((col8 >> 3) ^ (s & 7)) * 8;   // swizzled 16B-chunk position
    *(u16x8*)(Kc + ((size_t)bh * S_ + s) * DQK + swc) = w;
  } else {
    // V transpose: one 64(kv) x 64(d) tile per block via LDS
    int id = b - 4096;
    int bh = id >> 5, kt = id & 31;
    int tid = threadIdx.x;
    #pragma unroll
    for (int it = 0; it < 4; ++it) {
      int i = it * 256 + tid;
      int kv = i >> 4, dg = (i & 15) * 4;
      float4 v = *(const float4*)(V + ((size_t)bh * S_ + kt * 64 + kv) * D_ + dg);
      Ls[kv][dg + 0] = v.x; Ls[kv][dg + 1] = v.y;
      Ls[kv][dg + 2] = v.z; Ls[kv][dg + 3] = v.w;
    }
    __syncthreads();
    int d = tid >> 2, kvg = (tid & 3) * 16;
    u16x8 w0, w1;
    #pragma unroll
    for (int j = 0; j < 8; ++j) w0[j] = f2bf_rne(Ls[kvg + j][d]);
    #pragma unroll
    for (int j = 0; j < 8; ++j) w1[j] = f2bf_rne(Ls[kvg + 8 + j][d]);
    u16* dstrow = Vt + (((size_t)bh * 32 + kt) * 64 + d) * 64;
    int c0 = (tid & 3) * 2;                  // logical 16B-chunk of w0
    *(u16x8*)(dstrow + ((c0       ^ (d & 7)) * 8)) = w0;
    *(u16x8*)(dstrow + (((c0 + 1) ^ (d & 7)) * 8)) = w1;
  }
}

// ---------------- flash-attention main kernel -----------------------------
// Computes S^T = Kc . Qc^T so the P round-trip writes are ds_write_b64.
// Double-buffered LDS + global_load_lds DMA staging, 1 barrier/iter:
//   issue DMA(t+1) -> compute(t) -> vmcnt(0)+barrier   (T3-minimum pipeline)
// SPLIT=1: kv-halved grid (z=2), writes unnormalized O + l partials to ws.
template <int SPLIT>
__global__ __launch_bounds__(256, 2)
void fa3_kernel(const float* __restrict__ Q, const float* __restrict__ Qp,
                const u16* __restrict__ Kc, const u16* __restrict__ Vtg,
                float* __restrict__ out, float* __restrict__ Opart,
                float* __restrict__ lpart) {
  __shared__ alignas(16) u16 Ks[2][BK][DQK];   // 2 x 16KB, linear (DMA dest)
  __shared__ alignas(16) u16 Vt[2][D_][D_];    // 2 x 8KB, linear (DMA dest)
  __shared__ alignas(16) u16 Ps[BQ][LDV];      // 18KB

  const int tid  = threadIdx.x;
  const int wave = tid >> 6;
  const int lane = tid & 63;
  const int quad = lane >> 4;
  const int l16  = lane & 15;
  const int m0   = wave * 32;
  const int swz  = l16 & 7;                    // row&7 for all rows this lane reads

  const int bh = blockIdx.y;
  const int q0 = blockIdx.x * BQ;
  const int kz = SPLIT ? blockIdx.z : 0;
  const int kt0 = kz * 16;                 // kv tile offset (tiles of 64)
  const int NKT = SPLIT ? 16 : 32;

  // un-swizzled ds_read column offsets (u16 units), one per K-slice
  int kcol[4];
  #pragma unroll
  for (int ks = 0; ks < 4; ++ks) kcol[ks] = ((ks * 4 + quad) ^ swz) * 8;

  // ---- Q B-frags in registers, scale folded into conversion ----
  bf16x8 bq[2][4];
  #pragma unroll
  for (int nq = 0; nq < 2; ++nq)
    #pragma unroll
    for (int ks = 0; ks < 4; ++ks) {
      const float* base = (ks < 2 ? Q : Qp)
          + ((size_t)bh * S_ + q0 + m0 + nq * 16 + l16) * D_ + (ks & 1) * 32 + quad * 8;
      float4 v0 = *(const float4*)base;
      float4 v1 = *(const float4*)(base + 4);
      u16x8 w;
      w[0] = f2bf_rne(v0.x * COEF); w[1] = f2bf_rne(v0.y * COEF);
      w[2] = f2bf_rne(v0.z * COEF); w[3] = f2bf_rne(v0.w * COEF);
      w[4] = f2bf_rne(v1.x * COEF); w[5] = f2bf_rne(v1.y * COEF);
      w[6] = f2bf_rne(v1.z * COEF); w[7] = f2bf_rne(v1.w * COEF);
      bq[nq][ks] = __builtin_bit_cast(bf16x8, w);
    }

  // ---- staging pointers: thread owns 16B at (wave,j,lane)-linear offsets ----
  const int toff = wave * 512 + lane * 8;      // u16 units, 16B per lane
  const u16* kcp = Kc + ((size_t)bh * S_ + (size_t)kt0 * 64) * DQK + toff;
  const u16* vtp = Vtg + ((size_t)bh * 32 + kt0) * (size_t)(64 * 64) + toff;

  // prologue: stage tile 0 into buffer 0
  #pragma unroll
  for (int j = 0; j < 4; ++j) g2l16(kcp + j * 2048, &Ks[0][0][0] + toff + j * 2048);
  #pragma unroll
  for (int j = 0; j < 2; ++j) g2l16(vtp + j * 2048, &Vt[0][0][0] + toff + j * 2048);

  f32x4 acc[2][4];
  float l_part[2] = {0.f, 0.f};
  #pragma unroll
  for (int mtq = 0; mtq < 2; ++mtq)
    #pragma unroll
    for (int nt = 0; nt < 4; ++nt) acc[mtq][nt] = (f32x4){0.f, 0.f, 0.f, 0.f};

  __syncthreads();   // drains prologue DMA (vmcnt0) for all waves

  for (int kt = 0; kt < NKT; ++kt) {
    const int cur = kt & 1;
    const int nxt = kt + 1;
    // ---- issue DMA for next tile first; latency hides under compute ----
    if (nxt < NKT) {
      const u16* kg = kcp + (size_t)nxt * (64 * DQK);
      const u16* vg = vtp + (size_t)nxt * (64 * 64);
      u16* kl = &Ks[nxt & 1][0][0] + toff;
      u16* vl = &Vt[nxt & 1][0][0] + toff;
      #pragma unroll
      for (int j = 0; j < 4; ++j) g2l16(kg + j * 2048, kl + j * 2048);
      #pragma unroll
      for (int j = 0; j < 2; ++j) g2l16(vg + j * 2048, vl + j * 2048);
    }
    __builtin_amdgcn_sched_barrier(0);  // keep DMA issue ahead of compute

    // ---- S^T = Ks . Qc^T : m=kv (4 tiles), n=q (2 tiles of this wave) ----
    #pragma unroll
    for (int mt = 0; mt < 4; ++mt) {
      f32x4 s0 = (f32x4){0.f, 0.f, 0.f, 0.f};
      f32x4 s1 = (f32x4){0.f, 0.f, 0.f, 0.f};
      const u16* krow = &Ks[cur][mt * 16 + l16][0];
      #pragma unroll
      for (int ks = 0; ks < 4; ++ks) {
        bf16x8 ak = ld8(krow + kcol[ks]);
        s0 = __builtin_amdgcn_mfma_f32_16x16x32_bf16(ak, bq[0][ks], s0, 0, 0, 0);
        s1 = __builtin_amdgcn_mfma_f32_16x16x32_bf16(ak, bq[1][ks], s1, 0, 0, 0);
      }
      // C layout: row = kv = quad*4+r, col = q = l16. exp + b64 P-write.
      u16x4 w0, w1;
      float rs0 = 0.f, rs1 = 0.f;
      #pragma unroll
      for (int r = 0; r < 4; ++r) {
        float p0 = exp2f(s0[r]);
        float p1 = exp2f(s1[r]);
        w0[r] = f2bf_fast(p0); w1[r] = f2bf_fast(p1);
        rs0 += p0; rs1 += p1;
      }
      l_part[0] += rs0; l_part[1] += rs1;
      *(u16x4*)&Ps[m0 + l16][mt * 16 + quad * 4]      = w0;  // P[q][kv], contiguous kv
      *(u16x4*)&Ps[m0 + 16 + l16][mt * 16 + quad * 4] = w1;
    }

    // ---- O += P . V  (A = Ps rows natural [q][kv], B = Vt rows) ----
    bf16x8 pa[2][2];
    #pragma unroll
    for (int mtq = 0; mtq < 2; ++mtq)
      #pragma unroll
      for (int ks = 0; ks < 2; ++ks)
        pa[mtq][ks] = ld8(&Ps[m0 + mtq * 16 + l16][ks * 32 + quad * 8]);
    #pragma unroll
    for (int ntd = 0; ntd < 4; ++ntd) {
      const u16* vrow = &Vt[cur][ntd * 16 + l16][0];
      #pragma unroll
      for (int ks = 0; ks < 2; ++ks) {
        bf16x8 bv = ld8(vrow + kcol[ks]);   // same swizzled chunk offsets
        acc[0][ntd] = __builtin_amdgcn_mfma_f32_16x16x32_bf16(pa[0][ks], bv, acc[0][ntd], 0, 0, 0);
        acc[1][ntd] = __builtin_amdgcn_mfma_f32_16x16x32_bf16(pa[1][ks], bv, acc[1][ntd], 0, 0, 0);
      }
    }
    __syncthreads();  // drains this iter's DMA (vmcnt0) + publishes next buffer
  }

  // ---- epilogue ----
  float lsum[2];
  #pragma unroll
  for (int nq = 0; nq < 2; ++nq) {
    float v = l_part[nq];
    v += __shfl_xor(v, 16);
    v += __shfl_xor(v, 32);
    lsum[nq] = v;  // every lane: l for q = nq*16 + l16 (this block's kv range)
  }

  if (SPLIT) {
    #pragma unroll
    for (int mtq = 0; mtq < 2; ++mtq)
      #pragma unroll
      for (int r = 0; r < 4; ++r) {
        size_t rowb = ((size_t)kz * 65536 + (size_t)bh * S_
                       + q0 + m0 + mtq * 16 + quad * 4 + r) * D_;
        #pragma unroll
        for (int ntd = 0; ntd < 4; ++ntd)
          Opart[rowb + ntd * 16 + l16] = acc[mtq][ntd][r];
      }
    if (quad == 0) {
      #pragma unroll
      for (int nq = 0; nq < 2; ++nq)
        lpart[(size_t)kz * 65536 + (size_t)bh * S_ + q0 + m0 + nq * 16 + l16] = lsum[nq];
    }
  } else {
    #pragma unroll
    for (int mtq = 0; mtq < 2; ++mtq)
      #pragma unroll
      for (int r = 0; r < 4; ++r) {
        float inv = 1.0f / __shfl(lsum[mtq], quad * 4 + r);
        size_t rowb = ((size_t)bh * S_ + q0 + m0 + mtq * 16 + quad * 4 + r) * D_;
        #pragma unroll
        for (int ntd = 0; ntd < 4; ++ntd)
          out[rowb + ntd * 16 + l16] = acc[mtq][ntd][r] * inv;
      }
  }
}

// ---------------- combine: out = (O0 + O1) / (l0 + l1) --------------------
__global__ __launch_bounds__(256)
void combine_kernel(const float* __restrict__ Opart, const float* __restrict__ lpart,
                    float* __restrict__ out) {
  int t = blockIdx.x * 256 + threadIdx.x;   // 1,048,576 threads
  int row = t >> 4;
  int d4  = (t & 15) * 4;
  float4 o0 = *(const float4*)(Opart + (size_t)row * D_ + d4);
  float4 o1 = *(const float4*)(Opart + (size_t)65536 * D_ + (size_t)row * D_ + d4);
  float inv = 1.0f / (lpart[row] + lpart[65536 + row]);
  float4 o;
  o.x = (o0.x + o1.x) * inv; o.y = (o0.y + o1.y) * inv;
  o.z = (o0.z + o1.z) * inv; o.w = (o0.w + o1.w) * inv;
  *(float4*)(out + (size_t)row * D_ + d4) = o;
}

extern "C" void kernel_launch(void* const* d_in, const int* in_sizes, int n_in,
                              void* d_out, int out_size, void* d_ws, size_t ws_size,
                              hipStream_t stream) {
  const float* Q  = (const float*)d_in[0];
  const float* K  = (const float*)d_in[1];
  const float* V  = (const float*)d_in[2];
  const float* Qp = (const float*)d_in[3];
  const float* Kp = (const float*)d_in[4];
  float* out = (float*)d_out;

  const size_t nKc = (size_t)BH_ * S_ * DQK;   // 8.39M u16
  const size_t nVt = (size_t)BH_ * S_ * D_;    // 4.19M u16
  const size_t nO  = (size_t)2 * 65536 * D_;   // 8.39M f32
  const size_t nL  = (size_t)2 * 65536;        // 131072 f32
  const size_t needSplit = (nO + nL) * 4 + (nKc + nVt) * 2;  // ~59.3 MB

  if (ws_size >= needSplit) {
    float* Opart = (float*)d_ws;
    float* lpart = Opart + nO;
    u16* Kc = (u16*)(lpart + nL);
    u16* Vt = Kc + nKc;
    prep_kernel<<<dim3(4096 + 1024), dim3(256), 0, stream>>>(K, V, Kp, Kc, Vt);
    fa3_kernel<1><<<dim3(S_ / BQ, BH_, 2), dim3(256), 0, stream>>>(Q, Qp, Kc, Vt, nullptr, Opart, lpart);
    combine_kernel<<<dim3(4096), dim3(256), 0, stream>>>(Opart, lpart, out);
  } else {
    // ws >= 26 MB path (round-2 bench proved ws >= 42 MB)
    u16* Kc = (u16*)d_ws;
    u16* Vt = Kc + nKc;
    prep_kernel<<<dim3(4096 + 1024), dim3(256), 0, stream>>>(K, V, Kp, Kc, Vt);
    fa3_kernel<0><<<dim3(S_ / BQ, BH_, 1), dim3(256), 0, stream>>>(Q, Qp, Kc, Vt, out, nullptr, nullptr);
  }
}

// Round 2
// 193.010 us; speedup vs baseline: 1.1489x; 1.0942x over previous
//
#include <hip/hip_runtime.h>

#define BH_ 32
#define S_ 2048
#define D_ 64
#define DQK 128
#define BQ 128   // q rows per block (4 waves x 32 q-rows each)

typedef unsigned short u16;
typedef unsigned int u32;
typedef u16 u16x8 __attribute__((ext_vector_type(8)));
typedef u32 u32x4 __attribute__((ext_vector_type(4)));
typedef __bf16 bf16x8 __attribute__((ext_vector_type(8)));
typedef float f32x16 __attribute__((ext_vector_type(16)));

__device__ __forceinline__ u16 f2bf_rne(float f) {
  unsigned u = __builtin_bit_cast(unsigned, f);
  u += 0x7fffu + ((u >> 16) & 1u);
  return (u16)(u >> 16);
}
__device__ __forceinline__ bf16x8 ld8(const u16* p) {
  return __builtin_bit_cast(bf16x8, *(const u16x8*)p);
}
// 16B global -> LDS DMA. LDS dest must be wave-uniform base + lane*16.
__device__ __forceinline__ void g2l16(const u16* g, u16* l) {
  __builtin_amdgcn_global_load_lds(
      (const __attribute__((address_space(1))) unsigned int*)g,
      (__attribute__((address_space(3))) unsigned int*)l, 16, 0, 0);
}
__device__ __forceinline__ u32 cvtpk(float lo, float hi) {
  u32 r;
  asm("v_cvt_pk_bf16_f32 %0, %1, %2" : "=v"(r) : "v"(lo), "v"(hi));
  return r;
}
__device__ __forceinline__ void swap32(u32& a, u32& b) {
  asm("v_permlane32_swap_b32 %0, %1" : "+v"(a), "+v"(b));
}
__device__ __forceinline__ f32x16 zero16() {
  f32x16 z;
  #pragma unroll
  for (int i = 0; i < 16; ++i) z[i] = 0.f;
  return z;
}

#define COEF 0.1803368801111204f  // (1/8) * log2(e), folded into Q conversion

// ---------------- prep ----------------------------------------------------
// Kc: [bh][kt=32][chunk16B=16][kv=64][8 u16]  (chunk = k>>3 of the 128-dim
//     [K|Kp] concat) -> linear DMA image gives conflict-free b128 A-frag reads.
// Vt: [bh][kt=32][chunk=8][d=64][8 u16]  where element = V[kt*64+chunk*8+e][d].
__global__ __launch_bounds__(256)
void prep_kernel(const float* __restrict__ K, const float* __restrict__ V,
                 const float* __restrict__ Kp,
                 u16* __restrict__ Kc, u16* __restrict__ Vt) {
  __shared__ float Ls[64][65];
  int b = blockIdx.x;
  if (b < 4096) {
    int t = b * 256 + threadIdx.x;          // 1,048,576 threads
    int chunk = t & 15;
    int col8  = chunk * 8;
    int s     = (t >> 4) & 2047;
    int bh    = t >> 15;
    const float* src = (col8 < 64) ? (K  + ((size_t)bh * S_ + s) * D_ + col8)
                                   : (Kp + ((size_t)bh * S_ + s) * D_ + (col8 - 64));
    float4 v0 = *(const float4*)src;
    float4 v1 = *(const float4*)(src + 4);
    u16x8 w;
    w[0] = f2bf_rne(v0.x); w[1] = f2bf_rne(v0.y); w[2] = f2bf_rne(v0.z); w[3] = f2bf_rne(v0.w);
    w[4] = f2bf_rne(v1.x); w[5] = f2bf_rne(v1.y); w[6] = f2bf_rne(v1.z); w[7] = f2bf_rne(v1.w);
    int kt = s >> 6, kv = s & 63;
    *(u16x8*)(Kc + ((((size_t)bh * 32 + kt) * 16 + chunk) * 64 + kv) * 8) = w;
  } else {
    // V transpose: one 64(kv) x 64(d) tile per block via LDS
    int id = b - 4096;
    int bh = id >> 5, kt = id & 31;
    int tid = threadIdx.x;
    #pragma unroll
    for (int it = 0; it < 4; ++it) {
      int i = it * 256 + tid;
      int kv = i >> 4, dg = (i & 15) * 4;
      float4 v = *(const float4*)(V + ((size_t)bh * S_ + kt * 64 + kv) * D_ + dg);
      Ls[kv][dg + 0] = v.x; Ls[kv][dg + 1] = v.y;
      Ls[kv][dg + 2] = v.z; Ls[kv][dg + 3] = v.w;
    }
    __syncthreads();
    int d = tid >> 2, kvg = (tid & 3) * 16;
    u16x8 w0, w1;
    #pragma unroll
    for (int j = 0; j < 8; ++j) w0[j] = f2bf_rne(Ls[kvg + j][d]);
    #pragma unroll
    for (int j = 0; j < 8; ++j) w1[j] = f2bf_rne(Ls[kvg + 8 + j][d]);
    u16* base = Vt + ((size_t)bh * 32 + kt) * 4096;
    int c = (tid & 3) * 2;                   // kv-chunk of w0
    *(u16x8*)(base + ((size_t)(c * 64 + d)) * 8)       = w0;
    *(u16x8*)(base + ((size_t)((c + 1) * 64 + d)) * 8) = w1;
  }
}

// ---------------- flash-attention main kernel -----------------------------
// 32x32x16 MFMA, swapped QK^T (S^T = K.Q^T): lane (hi, q=lane&31) holds
// S^T regs r -> kv = (r&3)+8*(r>>2)+4*hi. P->bf16 + PV A-frags built fully
// in-register via cvt_pk_bf16 + permlane32_swap (no Ps LDS round-trip).
// LDS 48KB -> 3 blocks/CU. One barrier/iter double-buffered DMA pipeline.
template <int SPLIT>
__global__ __launch_bounds__(256, 3)
void fa3_kernel(const float* __restrict__ Q, const float* __restrict__ Qp,
                const u16* __restrict__ Kc, const u16* __restrict__ Vtg,
                float* __restrict__ out, float* __restrict__ Opart,
                float* __restrict__ lpart) {
  __shared__ alignas(16) u16 Ks[2][8192];   // [buf][chunk=16][kv=64][8]  2x16KB
  __shared__ alignas(16) u16 Vs[2][4096];   // [buf][chunk=8][d=64][8]    2x8KB

  const int tid  = threadIdx.x;
  const int wave = tid >> 6;
  const int lane = tid & 63;
  const int l32  = lane & 31;
  const int hi   = lane >> 5;

  const int bh = blockIdx.y;
  const int qw = blockIdx.x * BQ + wave * 32;   // this wave's q base
  const int kz = SPLIT ? blockIdx.z : 0;
  const int kt0 = kz * 16;
  const int NKT = SPLIT ? 16 : 32;

  // ---- Q B-frags: bq[kstep][j] = Qc[q = qw+l32][kstep*16 + hi*8 + j] ----
  bf16x8 bq[8];
  #pragma unroll
  for (int kstep = 0; kstep < 8; ++kstep) {
    int k0 = kstep * 16 + hi * 8;            // wave-uniform Q/Qp select per kstep
    const float* src = (k0 < 64)
        ? (Q  + ((size_t)bh * S_ + qw + l32) * D_ + k0)
        : (Qp + ((size_t)bh * S_ + qw + l32) * D_ + (k0 - 64));
    float4 v0 = *(const float4*)src;
    float4 v1 = *(const float4*)(src + 4);
    u16x8 w;
    w[0] = f2bf_rne(v0.x * COEF); w[1] = f2bf_rne(v0.y * COEF);
    w[2] = f2bf_rne(v0.z * COEF); w[3] = f2bf_rne(v0.w * COEF);
    w[4] = f2bf_rne(v1.x * COEF); w[5] = f2bf_rne(v1.y * COEF);
    w[6] = f2bf_rne(v1.z * COEF); w[7] = f2bf_rne(v1.w * COEF);
    bq[kstep] = __builtin_bit_cast(bf16x8, w);
  }

  // ---- staging pointers: thread owns 16B at tid-linear offsets ----
  const u16* kcp = Kc  + ((size_t)bh * 32 + kt0) * 8192 + tid * 8;
  const u16* vtp = Vtg + ((size_t)bh * 32 + kt0) * 4096 + tid * 8;

  // prologue: stage tile 0 into buffer 0
  #pragma unroll
  for (int j = 0; j < 4; ++j) g2l16(kcp + j * 2048, &Ks[0][0] + tid * 8 + j * 2048);
  #pragma unroll
  for (int j = 0; j < 2; ++j) g2l16(vtp + j * 2048, &Vs[0][0] + tid * 8 + j * 2048);

  f32x16 accd[2];
  accd[0] = zero16(); accd[1] = zero16();
  float l_part = 0.f;

  __syncthreads();   // drains prologue DMA (vmcnt0) for all waves

  for (int kt = 0; kt < NKT; ++kt) {
    const int cur = kt & 1;
    const int nxt = kt + 1;
    // ---- issue DMA for next tile first; latency hides under compute ----
    if (nxt < NKT) {
      const u16* kg = kcp + (size_t)nxt * 8192;
      const u16* vg = vtp + (size_t)nxt * 4096;
      u16* kl = &Ks[nxt & 1][0] + tid * 8;
      u16* vl = &Vs[nxt & 1][0] + tid * 8;
      #pragma unroll
      for (int j = 0; j < 4; ++j) g2l16(kg + j * 2048, kl + j * 2048);
      #pragma unroll
      for (int j = 0; j < 2; ++j) g2l16(vg + j * 2048, vl + j * 2048);
    }
    __builtin_amdgcn_sched_barrier(0);  // keep DMA issue ahead of compute

    const u16* ksb = &Ks[cur][0];
    const u16* vsb = &Vs[cur][0];

    // ---- S^T = K . Q^T : two kv-halves of 32, K-dim 128 in 8 steps ----
    f32x16 s[2];
    s[0] = zero16(); s[1] = zero16();
    #pragma unroll
    for (int kstep = 0; kstep < 8; ++kstep) {
      bf16x8 akA = ld8(ksb + (((kstep * 2 + hi) * 64) + l32) * 8);
      bf16x8 akB = ld8(ksb + (((kstep * 2 + hi) * 64) + 32 + l32) * 8);
      s[0] = __builtin_amdgcn_mfma_f32_32x32x16_bf16(akA, bq[kstep], s[0], 0, 0, 0);
      s[1] = __builtin_amdgcn_mfma_f32_32x32x16_bf16(akB, bq[kstep], s[1], 0, 0, 0);
    }

    // ---- softmax numerator + in-register P redistribution + PV ----
    #pragma unroll
    for (int h = 0; h < 2; ++h) {
      #pragma unroll
      for (int r = 0; r < 16; ++r) {
        float ev = exp2f(s[h][r]);
        s[h][r] = ev;               // reuse regs: s now holds P (f32)
        l_part += ev;
      }
      #pragma unroll
      for (int k2 = 0; k2 < 2; ++k2) {
        // word0/word2 from regs {0,1}/{4,5}; word1/word3 from {2,3}/{6,7}
        u32 a0 = cvtpk(s[h][8 * k2 + 0], s[h][8 * k2 + 1]);
        u32 b0 = cvtpk(s[h][8 * k2 + 4], s[h][8 * k2 + 5]);
        swap32(a0, b0);
        u32 a1 = cvtpk(s[h][8 * k2 + 2], s[h][8 * k2 + 3]);
        u32 b1 = cvtpk(s[h][8 * k2 + 6], s[h][8 * k2 + 7]);
        swap32(a1, b1);
        u32x4 pw; pw[0] = a0; pw[1] = a1; pw[2] = b0; pw[3] = b1;
        bf16x8 pa = __builtin_bit_cast(bf16x8, pw);
        int ksl = 2 * h + k2;                // kv 16-slice index in [0,4)
        #pragma unroll
        for (int dt = 0; dt < 2; ++dt) {
          bf16x8 bv = ld8(vsb + (((ksl * 2 + hi) * 64) + dt * 32 + l32) * 8);
          accd[dt] = __builtin_amdgcn_mfma_f32_32x32x16_bf16(pa, bv, accd[dt], 0, 0, 0);
        }
      }
    }
    __syncthreads();  // drains this iter's DMA (vmcnt0) + publishes next buffer
  }

  // ---- epilogue: l[q=l32] = own half + partner half ----
  float lsum = l_part + __shfl_xor(l_part, 32);

  if (SPLIT) {
    #pragma unroll
    for (int r = 0; r < 16; ++r) {
      int qrow = (r & 3) + 8 * (r >> 2) + 4 * hi;
      size_t rowb = ((size_t)kz * 65536 + (size_t)bh * S_ + qw + qrow) * D_;
      Opart[rowb + l32]      = accd[0][r];
      Opart[rowb + 32 + l32] = accd[1][r];
    }
    if (hi == 0)
      lpart[(size_t)kz * 65536 + (size_t)bh * S_ + qw + l32] = lsum;
  } else {
    #pragma unroll
    for (int r = 0; r < 16; ++r) {
      int qrow = (r & 3) + 8 * (r >> 2) + 4 * hi;
      float inv = 1.0f / __shfl(lsum, qrow);
      size_t rowb = ((size_t)bh * S_ + qw + qrow) * D_;
      out[rowb + l32]      = accd[0][r] * inv;
      out[rowb + 32 + l32] = accd[1][r] * inv;
    }
  }
}

// ---------------- combine: out = (O0 + O1) / (l0 + l1) --------------------
__global__ __launch_bounds__(256)
void combine_kernel(const float* __restrict__ Opart, const float* __restrict__ lpart,
                    float* __restrict__ out) {
  int t = blockIdx.x * 256 + threadIdx.x;   // 1,048,576 threads
  int row = t >> 4;
  int d4  = (t & 15) * 4;
  float4 o0 = *(const float4*)(Opart + (size_t)row * D_ + d4);
  float4 o1 = *(const float4*)(Opart + (size_t)65536 * D_ + (size_t)row * D_ + d4);
  float inv = 1.0f / (lpart[row] + lpart[65536 + row]);
  float4 o;
  o.x = (o0.x + o1.x) * inv; o.y = (o0.y + o1.y) * inv;
  o.z = (o0.z + o1.z) * inv; o.w = (o0.w + o1.w) * inv;
  *(float4*)(out + (size_t)row * D_ + d4) = o;
}

extern "C" void kernel_launch(void* const* d_in, const int* in_sizes, int n_in,
                              void* d_out, int out_size, void* d_ws, size_t ws_size,
                              hipStream_t stream) {
  const float* Q  = (const float*)d_in[0];
  const float* K  = (const float*)d_in[1];
  const float* V  = (const float*)d_in[2];
  const float* Qp = (const float*)d_in[3];
  const float* Kp = (const float*)d_in[4];
  float* out = (float*)d_out;

  const size_t nKc = (size_t)BH_ * S_ * DQK;   // 8.39M u16
  const size_t nVt = (size_t)BH_ * S_ * D_;    // 4.19M u16
  const size_t nO  = (size_t)2 * 65536 * D_;   // 8.39M f32
  const size_t nL  = (size_t)2 * 65536;        // 131072 f32
  const size_t needSplit = (nO + nL) * 4 + (nKc + nVt) * 2;  // ~59.3 MB

  if (ws_size >= needSplit) {
    float* Opart = (float*)d_ws;
    float* lpart = Opart + nO;
    u16* Kc = (u16*)(lpart + nL);
    u16* Vt = Kc + nKc;
    prep_kernel<<<dim3(4096 + 1024), dim3(256), 0, stream>>>(K, V, Kp, Kc, Vt);
    fa3_kernel<1><<<dim3(S_ / BQ, BH_, 2), dim3(256), 0, stream>>>(Q, Qp, Kc, Vt, nullptr, Opart, lpart);
    combine_kernel<<<dim3(4096), dim3(256), 0, stream>>>(Opart, lpart, out);
  } else {
    // ws >= 26 MB path
    u16* Kc = (u16*)d_ws;
    u16* Vt = Kc + nKc;
    prep_kernel<<<dim3(4096 + 1024), dim3(256), 0, stream>>>(K, V, Kp, Kc, Vt);
    fa3_kernel<0><<<dim3(S_ / BQ, BH_, 1), dim3(256), 0, stream>>>(Q, Qp, Kc, Vt, out, nullptr, nullptr);
  }
}

// Round 5
// 192.948 us; speedup vs baseline: 1.1493x; 1.0003x over previous
//
#include <hip/hip_runtime.h>

#define BH_ 32
#define S_ 2048
#define D_ 64
#define DQK 128
#define BQ 256   // q rows per block (8 waves x 32 q-rows each)

typedef unsigned short u16;
typedef unsigned int u32;
typedef u16 u16x8 __attribute__((ext_vector_type(8)));
typedef u32 u32x4 __attribute__((ext_vector_type(4)));
typedef __bf16 bf16x8 __attribute__((ext_vector_type(8)));
typedef float f32x16 __attribute__((ext_vector_type(16)));

__device__ __forceinline__ u16 f2bf_rne(float f) {
  unsigned u = __builtin_bit_cast(unsigned, f);
  u += 0x7fffu + ((u >> 16) & 1u);
  return (u16)(u >> 16);
}
__device__ __forceinline__ bf16x8 ld8(const u16* p) {
  return __builtin_bit_cast(bf16x8, *(const u16x8*)p);
}
// 16B global -> LDS DMA. LDS dest must be wave-uniform base + lane*16.
__device__ __forceinline__ void g2l16(const u16* g, u16* l) {
  __builtin_amdgcn_global_load_lds(
      (const __attribute__((address_space(1))) unsigned int*)g,
      (__attribute__((address_space(3))) unsigned int*)l, 16, 0, 0);
}
__device__ __forceinline__ u32 cvtpk(float lo, float hi) {
  u32 r;
  asm("v_cvt_pk_bf16_f32 %0, %1, %2" : "=v"(r) : "v"(lo), "v"(hi));
  return r;
}
__device__ __forceinline__ void swap32(u32& a, u32& b) {
  asm("v_permlane32_swap_b32 %0, %1" : "+v"(a), "+v"(b));
}
// NOTE (R3/R4 lesson): do NOT feed MFMA accumulator registers straight into
// inline-asm (e.g. a bare v_exp_f32). The MFMA-dst -> VALU-read hazard nops
// are inserted by the compiler only for compiler-visible consumers; inline-asm
// uses can go unprotected -> intermittent stale reads (absmax ~0.17 fails).
// exp2f's OCML sequence touches the value with real IR ops first = protected.
__device__ __forceinline__ f32x16 zero16() {
  f32x16 z;
  #pragma unroll
  for (int i = 0; i < 16; ++i) z[i] = 0.f;
  return z;
}

#define COEF 0.1803368801111204f  // (1/8) * log2(e), folded into Q conversion

// ---------------- prep ----------------------------------------------------
// Kc: [bh][kt=32][chunk16B=16][kv=64][8 u16]  (chunk = k>>3 of the 128-dim
//     [K|Kp] concat) -> linear DMA image gives conflict-free b128 A-frag reads.
// Vt: [bh][kt=32][chunk=8][d=64][8 u16]  where element = V[kt*64+chunk*8+e][d].
__global__ __launch_bounds__(256)
void prep_kernel(const float* __restrict__ K, const float* __restrict__ V,
                 const float* __restrict__ Kp,
                 u16* __restrict__ Kc, u16* __restrict__ Vt) {
  __shared__ float Ls[64][65];
  int b = blockIdx.x;
  if (b < 4096) {
    int t = b * 256 + threadIdx.x;          // 1,048,576 threads
    int chunk = t & 15;
    int col8  = chunk * 8;
    int s     = (t >> 4) & 2047;
    int bh    = t >> 15;
    const float* src = (col8 < 64) ? (K  + ((size_t)bh * S_ + s) * D_ + col8)
                                   : (Kp + ((size_t)bh * S_ + s) * D_ + (col8 - 64));
    float4 v0 = *(const float4*)src;
    float4 v1 = *(const float4*)(src + 4);
    u16x8 w;
    w[0] = f2bf_rne(v0.x); w[1] = f2bf_rne(v0.y); w[2] = f2bf_rne(v0.z); w[3] = f2bf_rne(v0.w);
    w[4] = f2bf_rne(v1.x); w[5] = f2bf_rne(v1.y); w[6] = f2bf_rne(v1.z); w[7] = f2bf_rne(v1.w);
    int kt = s >> 6, kv = s & 63;
    *(u16x8*)(Kc + ((((size_t)bh * 32 + kt) * 16 + chunk) * 64 + kv) * 8) = w;
  } else {
    // V transpose: one 64(kv) x 64(d) tile per block via LDS
    int id = b - 4096;
    int bh = id >> 5, kt = id & 31;
    int tid = threadIdx.x;
    #pragma unroll
    for (int it = 0; it < 4; ++it) {
      int i = it * 256 + tid;
      int kv = i >> 4, dg = (i & 15) * 4;
      float4 v = *(const float4*)(V + ((size_t)bh * S_ + kt * 64 + kv) * D_ + dg);
      Ls[kv][dg + 0] = v.x; Ls[kv][dg + 1] = v.y;
      Ls[kv][dg + 2] = v.z; Ls[kv][dg + 3] = v.w;
    }
    __syncthreads();
    int d = tid >> 2, kvg = (tid & 3) * 16;
    u16x8 w0, w1;
    #pragma unroll
    for (int j = 0; j < 8; ++j) w0[j] = f2bf_rne(Ls[kvg + j][d]);
    #pragma unroll
    for (int j = 0; j < 8; ++j) w1[j] = f2bf_rne(Ls[kvg + 8 + j][d]);
    u16* base = Vt + ((size_t)bh * 32 + kt) * 4096;
    int c = (tid & 3) * 2;                   // kv-chunk of w0
    *(u16x8*)(base + ((size_t)(c * 64 + d)) * 8)       = w0;
    *(u16x8*)(base + ((size_t)((c + 1) * 64 + d)) * 8) = w1;
  }
}

// ---------------- flash-attention main kernel -----------------------------
// 32x32x16 MFMA, swapped QK^T (S^T = K.Q^T): lane (hi, q=lane&31) holds
// S^T regs r -> kv = (r&3)+8*(r>>2)+4*hi. P->bf16 + PV A-frags built fully
// in-register via cvt_pk_bf16 + permlane32_swap (no Ps LDS round-trip).
// 8 waves / 512 threads: 24KB/tile staging amortized over 8 waves; grid 512
// = exactly 2 blocks/CU resident, zero tail. K,V both DMA-double-buffered,
// one barrier per iteration. Softmax path byte-identical to passing R2.
template <int SPLIT>
__global__ __launch_bounds__(512, 4)
void fa3_kernel(const float* __restrict__ Q, const float* __restrict__ Qp,
                const u16* __restrict__ Kc, const u16* __restrict__ Vtg,
                float* __restrict__ out, float* __restrict__ Opart,
                float* __restrict__ lpart) {
  __shared__ alignas(16) u16 Ks[2][8192];   // [buf][chunk=16][kv=64][8]  2x16KB
  __shared__ alignas(16) u16 Vs[2][4096];   // [buf][chunk=8][d=64][8]    2x8KB

  const int tid  = threadIdx.x;
  const int wave = tid >> 6;                // 0..7
  const int lane = tid & 63;
  const int l32  = lane & 31;
  const int hi   = lane >> 5;

  const int bh = blockIdx.y;
  const int qw = blockIdx.x * BQ + wave * 32;   // this wave's q base
  const int kz = SPLIT ? blockIdx.z : 0;
  const int kt0 = kz * 16;
  const int NKT = SPLIT ? 16 : 32;

  // ---- Q B-frags: bq[kstep][j] = Qc[q = qw+l32][kstep*16 + hi*8 + j] ----
  bf16x8 bq[8];
  #pragma unroll
  for (int kstep = 0; kstep < 8; ++kstep) {
    int k0 = kstep * 16 + hi * 8;            // wave-uniform Q/Qp select per kstep
    const float* src = (k0 < 64)
        ? (Q  + ((size_t)bh * S_ + qw + l32) * D_ + k0)
        : (Qp + ((size_t)bh * S_ + qw + l32) * D_ + (k0 - 64));
    float4 v0 = *(const float4*)src;
    float4 v1 = *(const float4*)(src + 4);
    u16x8 w;
    w[0] = f2bf_rne(v0.x * COEF); w[1] = f2bf_rne(v0.y * COEF);
    w[2] = f2bf_rne(v0.z * COEF); w[3] = f2bf_rne(v0.w * COEF);
    w[4] = f2bf_rne(v1.x * COEF); w[5] = f2bf_rne(v1.y * COEF);
    w[6] = f2bf_rne(v1.z * COEF); w[7] = f2bf_rne(v1.w * COEF);
    bq[kstep] = __builtin_bit_cast(bf16x8, w);
  }

  // ---- staging pointers: thread owns 16B at tid-linear offsets ----
  // 512 threads x 16B = 8KB per batch: K tile = 2 batches, V tile = 1.
  const u16* kcp = Kc  + ((size_t)bh * 32 + kt0) * 8192 + tid * 8;
  const u16* vtp = Vtg + ((size_t)bh * 32 + kt0) * 4096 + tid * 8;

  // prologue: stage tile 0 into buffer 0
  #pragma unroll
  for (int j = 0; j < 2; ++j) g2l16(kcp + j * 4096, &Ks[0][0] + tid * 8 + j * 4096);
  g2l16(vtp, &Vs[0][0] + tid * 8);

  f32x16 accd[2];
  accd[0] = zero16(); accd[1] = zero16();
  float l_part = 0.f;

  __syncthreads();   // drains prologue DMA (vmcnt0) for all waves

  for (int kt = 0; kt < NKT; ++kt) {
    const int cur = kt & 1;
    const int nxt = kt + 1;
    // ---- issue DMA for next tile first; latency hides under compute ----
    if (nxt < NKT) {
      const u16* kg = kcp + (size_t)nxt * 8192;
      u16* kl = &Ks[nxt & 1][0] + tid * 8;
      #pragma unroll
      for (int j = 0; j < 2; ++j) g2l16(kg + j * 4096, kl + j * 4096);
      g2l16(vtp + (size_t)nxt * 4096, &Vs[nxt & 1][0] + tid * 8);
    }
    __builtin_amdgcn_sched_barrier(0);  // keep DMA issue ahead of compute

    const u16* ksb = &Ks[cur][0];
    const u16* vsb = &Vs[cur][0];

    // ---- S^T = K . Q^T : two kv-halves of 32, K-dim 128 in 8 steps ----
    f32x16 s[2];
    s[0] = zero16(); s[1] = zero16();
    #pragma unroll
    for (int kstep = 0; kstep < 8; ++kstep) {
      bf16x8 akA = ld8(ksb + (((kstep * 2 + hi) * 64) + l32) * 8);
      bf16x8 akB = ld8(ksb + (((kstep * 2 + hi) * 64) + 32 + l32) * 8);
      s[0] = __builtin_amdgcn_mfma_f32_32x32x16_bf16(akA, bq[kstep], s[0], 0, 0, 0);
      s[1] = __builtin_amdgcn_mfma_f32_32x32x16_bf16(akB, bq[kstep], s[1], 0, 0, 0);
    }

    // ---- softmax numerator + in-register P redistribution + PV ----
    #pragma unroll
    for (int h = 0; h < 2; ++h) {
      #pragma unroll
      for (int r = 0; r < 16; ++r) {
        float ev = exp2f(s[h][r]);
        s[h][r] = ev;               // reuse regs: s now holds P (f32)
        l_part += ev;
      }
      #pragma unroll
      for (int k2 = 0; k2 < 2; ++k2) {
        // word0/word2 from regs {0,1}/{4,5}; word1/word3 from {2,3}/{6,7}
        u32 a0 = cvtpk(s[h][8 * k2 + 0], s[h][8 * k2 + 1]);
        u32 b0 = cvtpk(s[h][8 * k2 + 4], s[h][8 * k2 + 5]);
        swap32(a0, b0);
        u32 a1 = cvtpk(s[h][8 * k2 + 2], s[h][8 * k2 + 3]);
        u32 b1 = cvtpk(s[h][8 * k2 + 6], s[h][8 * k2 + 7]);
        swap32(a1, b1);
        u32x4 pw; pw[0] = a0; pw[1] = a1; pw[2] = b0; pw[3] = b1;
        bf16x8 pa = __builtin_bit_cast(bf16x8, pw);
        int ksl = 2 * h + k2;                // kv 16-slice index in [0,4)
        #pragma unroll
        for (int dt = 0; dt < 2; ++dt) {
          bf16x8 bv = ld8(vsb + (((ksl * 2 + hi) * 64) + dt * 32 + l32) * 8);
          accd[dt] = __builtin_amdgcn_mfma_f32_32x32x16_bf16(pa, bv, accd[dt], 0, 0, 0);
        }
      }
    }
    __syncthreads();  // drains this iter's DMA (vmcnt0) + publishes next buffer
  }

  // ---- epilogue: l[q=l32] = own half + partner half ----
  float lsum = l_part + __shfl_xor(l_part, 32);

  if (SPLIT) {
    #pragma unroll
    for (int r = 0; r < 16; ++r) {
      int qrow = (r & 3) + 8 * (r >> 2) + 4 * hi;
      size_t rowb = ((size_t)kz * 65536 + (size_t)bh * S_ + qw + qrow) * D_;
      Opart[rowb + l32]      = accd[0][r];
      Opart[rowb + 32 + l32] = accd[1][r];
    }
    if (hi == 0)
      lpart[(size_t)kz * 65536 + (size_t)bh * S_ + qw + l32] = lsum;
  } else {
    #pragma unroll
    for (int r = 0; r < 16; ++r) {
      int qrow = (r & 3) + 8 * (r >> 2) + 4 * hi;
      float inv = 1.0f / __shfl(lsum, qrow);
      size_t rowb = ((size_t)bh * S_ + qw + qrow) * D_;
      out[rowb + l32]      = accd[0][r] * inv;
      out[rowb + 32 + l32] = accd[1][r] * inv;
    }
  }
}

// ---------------- combine: out = (O0 + O1) / (l0 + l1) --------------------
__global__ __launch_bounds__(256)
void combine_kernel(const float* __restrict__ Opart, const float* __restrict__ lpart,
                    float* __restrict__ out) {
  int t = blockIdx.x * 256 + threadIdx.x;   // 1,048,576 threads
  int row = t >> 4;
  int d4  = (t & 15) * 4;
  float4 o0 = *(const float4*)(Opart + (size_t)row * D_ + d4);
  float4 o1 = *(const float4*)(Opart + (size_t)65536 * D_ + (size_t)row * D_ + d4);
  float inv = 1.0f / (lpart[row] + lpart[65536 + row]);
  float4 o;
  o.x = (o0.x + o1.x) * inv; o.y = (o0.y + o1.y) * inv;
  o.z = (o0.z + o1.z) * inv; o.w = (o0.w + o1.w) * inv;
  *(float4*)(out + (size_t)row * D_ + d4) = o;
}

extern "C" void kernel_launch(void* const* d_in, const int* in_sizes, int n_in,
                              void* d_out, int out_size, void* d_ws, size_t ws_size,
                              hipStream_t stream) {
  const float* Q  = (const float*)d_in[0];
  const float* K  = (const float*)d_in[1];
  const float* V  = (const float*)d_in[2];
  const float* Qp = (const float*)d_in[3];
  const float* Kp = (const float*)d_in[4];
  float* out = (float*)d_out;

  const size_t nKc = (size_t)BH_ * S_ * DQK;   // 8.39M u16
  const size_t nVt = (size_t)BH_ * S_ * D_;    // 4.19M u16
  const size_t nO  = (size_t)2 * 65536 * D_;   // 8.39M f32
  const size_t nL  = (size_t)2 * 65536;        // 131072 f32
  const size_t needSplit = (nO + nL) * 4 + (nKc + nVt) * 2;  // ~59.3 MB

  if (ws_size >= needSplit) {
    float* Opart = (float*)d_ws;
    float* lpart = Opart + nO;
    u16* Kc = (u16*)(lpart + nL);
    u16* Vt = Kc + nKc;
    prep_kernel<<<dim3(4096 + 1024), dim3(256), 0, stream>>>(K, V, Kp, Kc, Vt);
    fa3_kernel<1><<<dim3(S_ / BQ, BH_, 2), dim3(512), 0, stream>>>(Q, Qp, Kc, Vt, nullptr, Opart, lpart);
    combine_kernel<<<dim3(4096), dim3(256), 0, stream>>>(Opart, lpart, out);
  } else {
    // ws >= 26 MB path
    u16* Kc = (u16*)d_ws;
    u16* Vt = Kc + nKc;
    prep_kernel<<<dim3(4096 + 1024), dim3(256), 0, stream>>>(K, V, Kp, Kc, Vt);
    fa3_kernel<0><<<dim3(S_ / BQ, BH_, 1), dim3(512), 0, stream>>>(Q, Qp, Kc, Vt, out, nullptr, nullptr);
  }
}

// Round 6
// 178.269 us; speedup vs baseline: 1.2440x; 1.0823x over previous
//
#include <hip/hip_runtime.h>

#define BH_ 32
#define S_ 2048
#define D_ 64
#define DQK 128
#define BQ 256   // q rows per block (8 waves x 32 q-rows each)

typedef unsigned short u16;
typedef unsigned int u32;
typedef u16 u16x8 __attribute__((ext_vector_type(8)));
typedef u32 u32x4 __attribute__((ext_vector_type(4)));
typedef __bf16 bf16x8 __attribute__((ext_vector_type(8)));
typedef float f32x16 __attribute__((ext_vector_type(16)));

__device__ __forceinline__ u16 f2bf_rne(float f) {
  unsigned u = __builtin_bit_cast(unsigned, f);
  u += 0x7fffu + ((u >> 16) & 1u);
  return (u16)(u >> 16);
}
__device__ __forceinline__ bf16x8 ld8(const u16* p) {
  return __builtin_bit_cast(bf16x8, *(const u16x8*)p);
}
// 16B global -> LDS DMA. LDS dest must be wave-uniform base + lane*16.
__device__ __forceinline__ void g2l16(const u16* g, u16* l) {
  __builtin_amdgcn_global_load_lds(
      (const __attribute__((address_space(1))) unsigned int*)g,
      (__attribute__((address_space(3))) unsigned int*)l, 16, 0, 0);
}
__device__ __forceinline__ u32 cvtpk(float lo, float hi) {
  u32 r;
  asm("v_cvt_pk_bf16_f32 %0, %1, %2" : "=v"(r) : "v"(lo), "v"(hi));
  return r;
}
__device__ __forceinline__ void swap32(u32& a, u32& b) {
  asm("v_permlane32_swap_b32 %0, %1" : "+v"(a), "+v"(b));
}
// NOTE (R3/R4 lesson): never feed MFMA accumulator regs straight into inline
// asm (bare v_exp_f32) -- MFMA-dst->VALU-read hazard nops are only inserted
// for compiler-visible consumers; asm uses went unprotected (absmax ~0.17).
// __builtin_amdgcn_exp2f is the compiler-visible bare v_exp_f32: hazard-safe,
// no OCML range-guard sequence (~5 VALU/call saved; scores are bounded).
__device__ __forceinline__ f32x16 zero16() {
  f32x16 z;
  #pragma unroll
  for (int i = 0; i < 16; ++i) z[i] = 0.f;
  return z;
}

#define COEF 0.1803368801111204f  // (1/8) * log2(e), folded into Q conversion

// ---------------- prep ----------------------------------------------------
// Kc: [bh][kt=32][chunk16B=16][kv=64][8 u16]  (chunk = k>>3 of the 128-dim
//     [K|Kp] concat) -> linear DMA image gives conflict-free b128 A-frag reads.
//     Lane mapping: kv fastest -> 16B stores are lane-contiguous (1KB/wave);
//     reads become 32B/lane @256B stride (all lines fully consumed via L2).
// Vt: [bh][kt=32][chunk=8][d=64][8 u16]  where element = V[kt*64+chunk*8+e][d].
__global__ __launch_bounds__(256)
void prep_kernel(const float* __restrict__ K, const float* __restrict__ V,
                 const float* __restrict__ Kp,
                 u16* __restrict__ Kc, u16* __restrict__ Vt) {
  __shared__ float Ls[64][65];
  int b = blockIdx.x;
  if (b < 4096) {
    int t = b * 256 + threadIdx.x;          // 1,048,576 threads
    int kv    = t & 63;
    int chunk = (t >> 6) & 15;
    int kt    = (t >> 10) & 31;
    int bh    = t >> 15;
    int s     = kt * 64 + kv;
    int col8  = chunk * 8;
    const float* src = (col8 < 64) ? (K  + ((size_t)bh * S_ + s) * D_ + col8)
                                   : (Kp + ((size_t)bh * S_ + s) * D_ + (col8 - 64));
    float4 v0 = *(const float4*)src;
    float4 v1 = *(const float4*)(src + 4);
    u16x8 w;
    w[0] = f2bf_rne(v0.x); w[1] = f2bf_rne(v0.y); w[2] = f2bf_rne(v0.z); w[3] = f2bf_rne(v0.w);
    w[4] = f2bf_rne(v1.x); w[5] = f2bf_rne(v1.y); w[6] = f2bf_rne(v1.z); w[7] = f2bf_rne(v1.w);
    *(u16x8*)(Kc + ((((size_t)bh * 32 + kt) * 16 + chunk) * 64 + kv) * 8) = w;
  } else {
    // V transpose: one 64(kv) x 64(d) tile per block via LDS
    int id = b - 4096;
    int bh = id >> 5, kt = id & 31;
    int tid = threadIdx.x;
    #pragma unroll
    for (int it = 0; it < 4; ++it) {
      int i = it * 256 + tid;
      int kv = i >> 4, dg = (i & 15) * 4;
      float4 v = *(const float4*)(V + ((size_t)bh * S_ + kt * 64 + kv) * D_ + dg);
      Ls[kv][dg + 0] = v.x; Ls[kv][dg + 1] = v.y;
      Ls[kv][dg + 2] = v.z; Ls[kv][dg + 3] = v.w;
    }
    __syncthreads();
    int d = tid >> 2, kvg = (tid & 3) * 16;
    u16x8 w0, w1;
    #pragma unroll
    for (int j = 0; j < 8; ++j) w0[j] = f2bf_rne(Ls[kvg + j][d]);
    #pragma unroll
    for (int j = 0; j < 8; ++j) w1[j] = f2bf_rne(Ls[kvg + 8 + j][d]);
    u16* base = Vt + ((size_t)bh * 32 + kt) * 4096;
    int c = (tid & 3) * 2;                   // kv-chunk of w0
    *(u16x8*)(base + ((size_t)(c * 64 + d)) * 8)       = w0;
    *(u16x8*)(base + ((size_t)((c + 1) * 64 + d)) * 8) = w1;
  }
}

// ---------------- flash-attention main kernel -----------------------------
// 32x32x16 MFMA, swapped QK^T (S^T = K.Q^T): lane (hi, q=lane&31) holds
// S^T regs r -> kv = (r&3)+8*(r>>2)+4*hi. P->bf16 + PV A-frags built fully
// in-register via cvt_pk_bf16 + permlane32_swap (no Ps LDS round-trip).
// 8 waves / 512 threads, 2 blocks/CU, K,V DMA-double-buffered, 1 barrier/iter.
// 1D grid + XCD swizzle: all q-blocks of one (bh,z) KV stream get block ids
// congruent mod 8 -> same XCD L2 (per-XCD working set ~3MB < 4MB).
template <int SPLIT>
__global__ __launch_bounds__(512, 4)
void fa3_kernel(const float* __restrict__ Q, const float* __restrict__ Qp,
                const u16* __restrict__ Kc, const u16* __restrict__ Vtg,
                float* __restrict__ out, float* __restrict__ Opart,
                float* __restrict__ lpart) {
  __shared__ alignas(16) u16 Ks[2][8192];   // [buf][chunk=16][kv=64][8]  2x16KB
  __shared__ alignas(16) u16 Vs[2][4096];   // [buf][chunk=8][d=64][8]    2x8KB

  const int tid  = threadIdx.x;
  const int wave = tid >> 6;                // 0..7
  const int lane = tid & 63;
  const int l32  = lane & 31;
  const int hi   = lane >> 5;

  const int id   = blockIdx.x;
  const int p    = SPLIT ? (id & 63) : (id & 31);   // (bh, z) pair index
  const int qblk = SPLIT ? (id >> 6) : (id >> 5);
  const int bh   = p & 31;
  const int kz   = SPLIT ? (p >> 5) : 0;

  const int qw = qblk * BQ + wave * 32;     // this wave's q base
  const int kt0 = kz * 16;
  const int NKT = SPLIT ? 16 : 32;

  // ---- Q B-frags: bq[kstep][j] = Qc[q = qw+l32][kstep*16 + hi*8 + j] ----
  bf16x8 bq[8];
  #pragma unroll
  for (int kstep = 0; kstep < 8; ++kstep) {
    int k0 = kstep * 16 + hi * 8;            // wave-uniform Q/Qp select per kstep
    const float* src = (k0 < 64)
        ? (Q  + ((size_t)bh * S_ + qw + l32) * D_ + k0)
        : (Qp + ((size_t)bh * S_ + qw + l32) * D_ + (k0 - 64));
    float4 v0 = *(const float4*)src;
    float4 v1 = *(const float4*)(src + 4);
    u16x8 w;
    w[0] = f2bf_rne(v0.x * COEF); w[1] = f2bf_rne(v0.y * COEF);
    w[2] = f2bf_rne(v0.z * COEF); w[3] = f2bf_rne(v0.w * COEF);
    w[4] = f2bf_rne(v1.x * COEF); w[5] = f2bf_rne(v1.y * COEF);
    w[6] = f2bf_rne(v1.z * COEF); w[7] = f2bf_rne(v1.w * COEF);
    bq[kstep] = __builtin_bit_cast(bf16x8, w);
  }

  // ---- staging pointers: thread owns 16B at tid-linear offsets ----
  // 512 threads x 16B = 8KB per batch: K tile = 2 batches, V tile = 1.
  const u16* kcp = Kc  + ((size_t)bh * 32 + kt0) * 8192 + tid * 8;
  const u16* vtp = Vtg + ((size_t)bh * 32 + kt0) * 4096 + tid * 8;

  // prologue: stage tile 0 into buffer 0
  #pragma unroll
  for (int j = 0; j < 2; ++j) g2l16(kcp + j * 4096, &Ks[0][0] + tid * 8 + j * 4096);
  g2l16(vtp, &Vs[0][0] + tid * 8);

  f32x16 accd[2];
  accd[0] = zero16(); accd[1] = zero16();
  float l_part = 0.f;

  __syncthreads();   // drains prologue DMA (vmcnt0) for all waves

  for (int kt = 0; kt < NKT; ++kt) {
    const int cur = kt & 1;
    const int nxt = kt + 1;
    // ---- issue DMA for next tile first; latency hides under compute ----
    if (nxt < NKT) {
      const u16* kg = kcp + (size_t)nxt * 8192;
      u16* kl = &Ks[nxt & 1][0] + tid * 8;
      #pragma unroll
      for (int j = 0; j < 2; ++j) g2l16(kg + j * 4096, kl + j * 4096);
      g2l16(vtp + (size_t)nxt * 4096, &Vs[nxt & 1][0] + tid * 8);
    }
    __builtin_amdgcn_sched_barrier(0);  // keep DMA issue ahead of compute

    const u16* ksb = &Ks[cur][0];
    const u16* vsb = &Vs[cur][0];

    // ---- S^T = K . Q^T : two kv-halves of 32, K-dim 128 in 8 steps ----
    f32x16 s[2];
    s[0] = zero16(); s[1] = zero16();
    #pragma unroll
    for (int kstep = 0; kstep < 8; ++kstep) {
      bf16x8 akA = ld8(ksb + (((kstep * 2 + hi) * 64) + l32) * 8);
      bf16x8 akB = ld8(ksb + (((kstep * 2 + hi) * 64) + 32 + l32) * 8);
      s[0] = __builtin_amdgcn_mfma_f32_32x32x16_bf16(akA, bq[kstep], s[0], 0, 0, 0);
      s[1] = __builtin_amdgcn_mfma_f32_32x32x16_bf16(akB, bq[kstep], s[1], 0, 0, 0);
    }

    // ---- softmax numerator + in-register P redistribution + PV ----
    #pragma unroll
    for (int h = 0; h < 2; ++h) {
      float rs0 = 0.f, rs1 = 0.f;          // split chains (reassoc-safe: +)
      #pragma unroll
      for (int r = 0; r < 8; ++r) {
        float e0 = __builtin_amdgcn_exp2f(s[h][r]);
        float e1 = __builtin_amdgcn_exp2f(s[h][8 + r]);
        s[h][r] = e0; s[h][8 + r] = e1;
        rs0 += e0; rs1 += e1;
      }
      l_part += rs0 + rs1;
      #pragma unroll
      for (int k2 = 0; k2 < 2; ++k2) {
        // word0/word2 from regs {0,1}/{4,5}; word1/word3 from {2,3}/{6,7}
        u32 a0 = cvtpk(s[h][8 * k2 + 0], s[h][8 * k2 + 1]);
        u32 b0 = cvtpk(s[h][8 * k2 + 4], s[h][8 * k2 + 5]);
        swap32(a0, b0);
        u32 a1 = cvtpk(s[h][8 * k2 + 2], s[h][8 * k2 + 3]);
        u32 b1 = cvtpk(s[h][8 * k2 + 6], s[h][8 * k2 + 7]);
        swap32(a1, b1);
        u32x4 pw; pw[0] = a0; pw[1] = a1; pw[2] = b0; pw[3] = b1;
        bf16x8 pa = __builtin_bit_cast(bf16x8, pw);
        int ksl = 2 * h + k2;                // kv 16-slice index in [0,4)
        #pragma unroll
        for (int dt = 0; dt < 2; ++dt) {
          bf16x8 bv = ld8(vsb + (((ksl * 2 + hi) * 64) + dt * 32 + l32) * 8);
          accd[dt] = __builtin_amdgcn_mfma_f32_32x32x16_bf16(pa, bv, accd[dt], 0, 0, 0);
        }
      }
    }
    __syncthreads();  // drains this iter's DMA (vmcnt0) + publishes next buffer
  }

  // ---- epilogue: l[q=l32] = own half + partner half ----
  float lsum = l_part + __shfl_xor(l_part, 32);

  if (SPLIT) {
    #pragma unroll
    for (int r = 0; r < 16; ++r) {
      int qrow = (r & 3) + 8 * (r >> 2) + 4 * hi;
      size_t rowb = ((size_t)kz * 65536 + (size_t)bh * S_ + qw + qrow) * D_;
      Opart[rowb + l32]      = accd[0][r];
      Opart[rowb + 32 + l32] = accd[1][r];
    }
    if (hi == 0)
      lpart[(size_t)kz * 65536 + (size_t)bh * S_ + qw + l32] = lsum;
  } else {
    #pragma unroll
    for (int r = 0; r < 16; ++r) {
      int qrow = (r & 3) + 8 * (r >> 2) + 4 * hi;
      float inv = 1.0f / __shfl(lsum, qrow);
      size_t rowb = ((size_t)bh * S_ + qw + qrow) * D_;
      out[rowb + l32]      = accd[0][r] * inv;
      out[rowb + 32 + l32] = accd[1][r] * inv;
    }
  }
}

// ---------------- combine: out = (O0 + O1) / (l0 + l1) --------------------
__global__ __launch_bounds__(256)
void combine_kernel(const float* __restrict__ Opart, const float* __restrict__ lpart,
                    float* __restrict__ out) {
  int t = blockIdx.x * 256 + threadIdx.x;   // 1,048,576 threads
  int row = t >> 4;
  int d4  = (t & 15) * 4;
  float4 o0 = *(const float4*)(Opart + (size_t)row * D_ + d4);
  float4 o1 = *(const float4*)(Opart + (size_t)65536 * D_ + (size_t)row * D_ + d4);
  float inv = 1.0f / (lpart[row] + lpart[65536 + row]);
  float4 o;
  o.x = (o0.x + o1.x) * inv; o.y = (o0.y + o1.y) * inv;
  o.z = (o0.z + o1.z) * inv; o.w = (o0.w + o1.w) * inv;
  *(float4*)(out + (size_t)row * D_ + d4) = o;
}

extern "C" void kernel_launch(void* const* d_in, const int* in_sizes, int n_in,
                              void* d_out, int out_size, void* d_ws, size_t ws_size,
                              hipStream_t stream) {
  const float* Q  = (const float*)d_in[0];
  const float* K  = (const float*)d_in[1];
  const float* V  = (const float*)d_in[2];
  const float* Qp = (const float*)d_in[3];
  const float* Kp = (const float*)d_in[4];
  float* out = (float*)d_out;

  const size_t nKc = (size_t)BH_ * S_ * DQK;   // 8.39M u16
  const size_t nVt = (size_t)BH_ * S_ * D_;    // 4.19M u16
  const size_t nO  = (size_t)2 * 65536 * D_;   // 8.39M f32
  const size_t nL  = (size_t)2 * 65536;        // 131072 f32
  const size_t needSplit = (nO + nL) * 4 + (nKc + nVt) * 2;  // ~59.3 MB

  if (ws_size >= needSplit) {
    float* Opart = (float*)d_ws;
    float* lpart = Opart + nO;
    u16* Kc = (u16*)(lpart + nL);
    u16* Vt = Kc + nKc;
    prep_kernel<<<dim3(4096 + 1024), dim3(256), 0, stream>>>(K, V, Kp, Kc, Vt);
    fa3_kernel<1><<<dim3((S_ / BQ) * BH_ * 2), dim3(512), 0, stream>>>(Q, Qp, Kc, Vt, nullptr, Opart, lpart);
    combine_kernel<<<dim3(4096), dim3(256), 0, stream>>>(Opart, lpart, out);
  } else {
    // ws >= 26 MB path
    u16* Kc = (u16*)d_ws;
    u16* Vt = Kc + nKc;
    prep_kernel<<<dim3(4096 + 1024), dim3(256), 0, stream>>>(K, V, Kp, Kc, Vt);
    fa3_kernel<0><<<dim3((S_ / BQ) * BH_), dim3(512), 0, stream>>>(Q, Qp, Kc, Vt, out, nullptr, nullptr);
  }
}